// Round 1
// baseline (797.785 us; speedup 1.0000x reference)
//
#include <hip/hip_runtime.h>
#include <hip/hip_bf16.h>
#include <math.h>

#define BSZ   8192
#define NCLS  57
#define DIM   256
#define NTASK 57
#define INV_T (1.0f/0.07f)

typedef short bf16x8 __attribute__((ext_vector_type(8)));
typedef float f32x4  __attribute__((ext_vector_type(4)));

__device__ __forceinline__ float bf2f(unsigned short h) {
    return __uint_as_float(((unsigned int)h) << 16);
}

// ---------------- kernel 1: logits stats (cls loss, uncertainty, task histogram) ----
__global__ void k_prep(const float* __restrict__ logits, const int* __restrict__ labels,
                       const int* __restrict__ tasks, float* __restrict__ u,
                       float* __restrict__ cls_sum, int* __restrict__ task_count) {
    int row  = blockIdx.x * 4 + (threadIdx.x >> 6);
    int lane = threadIdx.x & 63;
    float v = (lane < NCLS) ? logits[row * NCLS + lane] : -3.0e38f;
    float m = v;
    #pragma unroll
    for (int s = 1; s < 64; s <<= 1) m = fmaxf(m, __shfl_xor(m, s));
    float ex = (lane < NCLS) ? __expf(v - m) : 0.0f;
    float se = ex;
    #pragma unroll
    for (int s = 1; s < 64; s <<= 1) se += __shfl_xor(se, s);
    float lse = m + logf(se);
    float p = ex / se;
    float term = (lane < NCLS) ? p * logf(p + 1e-8f) : 0.0f;
    float ent = term;
    #pragma unroll
    for (int s = 1; s < 64; s <<= 1) ent += __shfl_xor(ent, s);
    ent = -ent;
    int lab = labels[row];
    float vl = __shfl(v, lab);           // logits[row][label]
    float cls = lse - vl;                // -log_softmax[label]
    if (lane == 0) {
        u[row] = ent / 4.04305127f;      // log(57)
        atomicAdd(cls_sum, cls);
        atomicAdd(&task_count[tasks[row]], 1);
    }
}

// ---------------- kernel 2: normalize embeddings -> bf16 ----------------------------
__global__ void k_norm(const float* __restrict__ emb, unsigned short* __restrict__ e) {
    int row  = blockIdx.x * 4 + (threadIdx.x >> 6);
    int lane = threadIdx.x & 63;
    const float4* src = reinterpret_cast<const float4*>(emb + row * DIM);
    float4 x = src[lane];
    float ss = x.x*x.x + x.y*x.y + x.z*x.z + x.w*x.w;
    #pragma unroll
    for (int s = 1; s < 64; s <<= 1) ss += __shfl_xor(ss, s);
    float sc = 1.0f / fmaxf(sqrtf(ss), 1e-12f);
    ushort4 o;
    __hip_bfloat16 b0 = __float2bfloat16(x.x * sc);
    __hip_bfloat16 b1 = __float2bfloat16(x.y * sc);
    __hip_bfloat16 b2 = __float2bfloat16(x.z * sc);
    __hip_bfloat16 b3 = __float2bfloat16(x.w * sc);
    o.x = *reinterpret_cast<unsigned short*>(&b0);
    o.y = *reinterpret_cast<unsigned short*>(&b1);
    o.z = *reinterpret_cast<unsigned short*>(&b2);
    o.w = *reinterpret_cast<unsigned short*>(&b3);
    *reinterpret_cast<ushort4*>(e + row * DIM + lane * 4) = o;
}

// ---------------- kernel 3: prefix sum over task histogram --------------------------
__global__ void k_prefix(const int* __restrict__ task_count, int* __restrict__ task_start,
                         int* __restrict__ task_cursor) {
    if (threadIdx.x == 0) {
        int acc = 0;
        for (int t = 0; t < NTASK; ++t) {
            task_start[t] = acc; task_cursor[t] = acc; acc += task_count[t];
        }
    }
}

// ---------------- kernel 4: counting-sort scatter -----------------------------------
__global__ void k_scatter(const int* __restrict__ tasks, int* __restrict__ task_cursor,
                          int* __restrict__ sorted) {
    int i = blockIdx.x * 256 + threadIdx.x;
    if (i < BSZ) {
        int pos = atomicAdd(&task_cursor[tasks[i]], 1);
        sorted[pos] = i;
    }
}

// ---------------- kernel 5: THE BIG ONE: neg_sum via bf16 MFMA ----------------------
// Block = 256 thr (4 waves). Block tile 128(M)x128(N); wave tile 32x128.
// A/B fragment (16x16x32): lane holds row (lane&15), 8 contiguous k at (lane>>4)*8.
// C/D: col = lane&15, row = (lane>>4)*4 + reg  [guide m89 verified].
__global__ __launch_bounds__(256) void k_negsum(const unsigned short* __restrict__ E,
                                                const int* __restrict__ tasks,
                                                float* __restrict__ neg_sum) {
    const int nbn = BSZ / 128;           // 64
    int bn = blockIdx.x % nbn;
    int bm = blockIdx.x / nbn;
    int wave = threadIdx.x >> 6;
    int lane = threadIdx.x & 63;
    int g  = lane >> 4;                  // 0..3
    int lr = lane & 15;
    int m0 = bm * 128 + wave * 32;
    int n0 = bn * 128;

    f32x4 acc[2][8] = {};
    const unsigned short* arow0 = E + (size_t)(m0 + lr) * DIM      + g * 8;
    const unsigned short* arow1 = E + (size_t)(m0 + 16 + lr) * DIM + g * 8;

    #pragma unroll
    for (int ks = 0; ks < 8; ++ks) {
        int ko = ks * 32;
        bf16x8 a0 = *reinterpret_cast<const bf16x8*>(arow0 + ko);
        bf16x8 a1 = *reinterpret_cast<const bf16x8*>(arow1 + ko);
        #pragma unroll
        for (int f = 0; f < 8; ++f) {
            bf16x8 b = *reinterpret_cast<const bf16x8*>(E + (size_t)(n0 + f * 16 + lr) * DIM + g * 8 + ko);
            acc[0][f] = __builtin_amdgcn_mfma_f32_16x16x32_bf16(a0, b, acc[0][f], 0, 0, 0);
            acc[1][f] = __builtin_amdgcn_mfma_f32_16x16x32_bf16(a1, b, acc[1][f], 0, 0, 0);
        }
    }

    int colt[8];
    #pragma unroll
    for (int f = 0; f < 8; ++f) colt[f] = tasks[n0 + f * 16 + lr];

    #pragma unroll
    for (int mi = 0; mi < 2; ++mi) {
        #pragma unroll
        for (int r = 0; r < 4; ++r) {
            int row = m0 + mi * 16 + g * 4 + r;
            int rt = tasks[row];
            float s = 0.0f;
            #pragma unroll
            for (int f = 0; f < 8; ++f) {
                float val = acc[mi][f][r] * INV_T;
                s += (colt[f] != rt) ? __expf(val) : 0.0f;
            }
            // reduce across the 16 lanes (lr) of this group
            s += __shfl_xor(s, 1); s += __shfl_xor(s, 2);
            s += __shfl_xor(s, 4); s += __shfl_xor(s, 8);
            if (lr == 0) atomicAdd(&neg_sum[row], s);
        }
    }
}

// ---------------- kernel 6: positive-pair loss (recompute dots, task-sorted) --------
__global__ __launch_bounds__(256) void k_pos(const unsigned short* __restrict__ E,
                                             const int* __restrict__ tasks,
                                             const int* __restrict__ sorted,
                                             const int* __restrict__ task_count,
                                             const int* __restrict__ task_start,
                                             const float* __restrict__ neg_sum,
                                             const float* __restrict__ u,
                                             float* __restrict__ contr_sum) {
    int p = blockIdx.x;
    int i = sorted[p];
    int t = tasks[i];
    int c = task_count[t];
    if (c < 2 || c >= BSZ) return;       // invalid row: no pos or no neg
    int st   = task_start[t];
    int wave = threadIdx.x >> 6;
    int lane = threadIdx.x & 63;

    ushort4 ei = *reinterpret_cast<const ushort4*>(E + (size_t)i * DIM + lane * 4);
    float e0 = bf2f(ei.x), e1 = bf2f(ei.y), e2 = bf2f(ei.z), e3 = bf2f(ei.w);
    float Ci = neg_sum[i] + 1e-8f;
    float local = 0.0f;

    for (int m = wave; m < c; m += 4) {
        int j = sorted[st + m];
        if (j == i) continue;
        ushort4 ej = *reinterpret_cast<const ushort4*>(E + (size_t)j * DIM + lane * 4);
        float d = e0 * bf2f(ej.x) + e1 * bf2f(ej.y) + e2 * bf2f(ej.z) + e3 * bf2f(ej.w);
        #pragma unroll
        for (int s = 1; s < 64; s <<= 1) d += __shfl_xor(d, s);
        float sv = d * INV_T;
        local += logf(__expf(sv) + Ci) - sv;   // -log(exp(s)/(exp(s)+C))
    }
    if (lane == 0) atomicAdd(contr_sum, u[i] * local);
}

// ---------------- kernel 7: final combine -------------------------------------------
__global__ void k_final(const int* __restrict__ task_count, const float* __restrict__ cls_sum,
                        const float* __restrict__ contr_sum, float* __restrict__ out) {
    int lane = threadIdx.x & 63;
    long long cnt = 0;
    if (lane < NTASK) {
        int c = task_count[lane];
        if (c >= 2 && c < BSZ) cnt = (long long)c * (c - 1);
    }
    #pragma unroll
    for (int s = 1; s < 64; s <<= 1) cnt += __shfl_xor(cnt, s);
    if (threadIdx.x == 0) {
        float cls = cls_sum[0] / (float)BSZ;
        float contr = (cnt > 0) ? (contr_sum[0] / (float)cnt) : 0.0f;
        out[0] = 0.7f * cls + 0.3f * contr;
    }
}

extern "C" void kernel_launch(void* const* d_in, const int* in_sizes, int n_in,
                              void* d_out, int out_size, void* d_ws, size_t ws_size,
                              hipStream_t stream) {
    const float* logits = (const float*)d_in[0];
    const float* emb    = (const float*)d_in[1];
    const int*   labels = (const int*)d_in[2];
    const int*   tasks  = (const int*)d_in[3];
    float* out = (float*)d_out;

    char* ws = (char*)d_ws;
    // workspace layout (4-byte units):
    // [0] cls_sum, [1] contr_sum, [2..65] task_count, [66..129] task_start,
    // [130..193] task_cursor, [256..] neg_sum[8192], then u[8192], sorted[8192], e bf16
    float* cls_sum     = (float*)ws;
    float* contr_sum   = cls_sum + 1;
    int*   task_count  = (int*)ws + 2;
    int*   task_start  = (int*)ws + 66;
    int*   task_cursor = (int*)ws + 130;
    float* neg_sum     = (float*)ws + 256;
    float* u           = neg_sum + BSZ;
    int*   sorted      = (int*)ws + 256 + 2 * BSZ;
    unsigned short* e  = (unsigned short*)(ws + (size_t)(256 + 3 * BSZ) * 4);

    // zero accumulators + histogram + neg_sum (ws is NOT re-poisoned between replays,
    // so this must run every call)
    hipMemsetAsync(ws, 0, (size_t)(256 + BSZ) * 4, stream);

    k_prep   <<<BSZ / 4,  256, 0, stream>>>(logits, labels, tasks, u, cls_sum, task_count);
    k_norm   <<<BSZ / 4,  256, 0, stream>>>(emb, e);
    k_prefix <<<1,        64,  0, stream>>>(task_count, task_start, task_cursor);
    k_scatter<<<BSZ / 256,256, 0, stream>>>(tasks, task_cursor, sorted);
    k_negsum <<<4096,     256, 0, stream>>>(e, tasks, neg_sum);
    k_pos    <<<BSZ,      256, 0, stream>>>(e, tasks, sorted, task_count, task_start,
                                            neg_sum, u, contr_sum);
    k_final  <<<1,        64,  0, stream>>>(task_count, cls_sum, contr_sum, out);
}

// Round 2
// 472.231 us; speedup vs baseline: 1.6894x; 1.6894x over previous
//
#include <hip/hip_runtime.h>
#include <hip/hip_bf16.h>
#include <math.h>

#define BSZ   8192
#define NCLS  57
#define DIM   256
#define NTASK 57
#define INV_T (1.0f/0.07f)
#define PAIR_CAP (2*1024*1024)   // 2M pairs (actual ~1.17M)

typedef short bf16x8 __attribute__((ext_vector_type(8)));
typedef float f32x4  __attribute__((ext_vector_type(4)));

__device__ __forceinline__ float bf2f(unsigned short h) {
    return __uint_as_float(((unsigned int)h) << 16);
}

// ---------------- kernel 1: logits stats (cls loss, uncertainty, task histogram) ----
__global__ void k_prep(const float* __restrict__ logits, const int* __restrict__ labels,
                       const int* __restrict__ tasks, float* __restrict__ u,
                       float* __restrict__ cls_sum, int* __restrict__ task_count) {
    int row  = blockIdx.x * 4 + (threadIdx.x >> 6);
    int lane = threadIdx.x & 63;
    float v = (lane < NCLS) ? logits[row * NCLS + lane] : -3.0e38f;
    float m = v;
    #pragma unroll
    for (int s = 1; s < 64; s <<= 1) m = fmaxf(m, __shfl_xor(m, s));
    float ex = (lane < NCLS) ? __expf(v - m) : 0.0f;
    float se = ex;
    #pragma unroll
    for (int s = 1; s < 64; s <<= 1) se += __shfl_xor(se, s);
    float lse = m + logf(se);
    float p = ex / se;
    float term = (lane < NCLS) ? p * logf(p + 1e-8f) : 0.0f;
    float ent = term;
    #pragma unroll
    for (int s = 1; s < 64; s <<= 1) ent += __shfl_xor(ent, s);
    ent = -ent;
    int lab = labels[row];
    float vl = __shfl(v, lab);           // logits[row][label]
    float cls = lse - vl;                // -log_softmax[label]
    if (lane == 0) {
        u[row] = ent / 4.04305127f;      // log(57)
        atomicAdd(cls_sum, cls);
        atomicAdd(&task_count[tasks[row]], 1);
    }
}

// ---------------- kernel 2: normalize embeddings -> bf16 ----------------------------
__global__ void k_norm(const float* __restrict__ emb, unsigned short* __restrict__ e) {
    int row  = blockIdx.x * 4 + (threadIdx.x >> 6);
    int lane = threadIdx.x & 63;
    const float4* src = reinterpret_cast<const float4*>(emb + row * DIM);
    float4 x = src[lane];
    float ss = x.x*x.x + x.y*x.y + x.z*x.z + x.w*x.w;
    #pragma unroll
    for (int s = 1; s < 64; s <<= 1) ss += __shfl_xor(ss, s);
    float sc = 1.0f / fmaxf(sqrtf(ss), 1e-12f);
    ushort4 o;
    __hip_bfloat16 b0 = __float2bfloat16(x.x * sc);
    __hip_bfloat16 b1 = __float2bfloat16(x.y * sc);
    __hip_bfloat16 b2 = __float2bfloat16(x.z * sc);
    __hip_bfloat16 b3 = __float2bfloat16(x.w * sc);
    o.x = *reinterpret_cast<unsigned short*>(&b0);
    o.y = *reinterpret_cast<unsigned short*>(&b1);
    o.z = *reinterpret_cast<unsigned short*>(&b2);
    o.w = *reinterpret_cast<unsigned short*>(&b3);
    *reinterpret_cast<ushort4*>(e + row * DIM + lane * 4) = o;
}

// ---------------- kernel 3: prefix sums (task starts + pair-buffer bases) -----------
__global__ void k_prefix(const int* __restrict__ task_count, int* __restrict__ task_start,
                         int* __restrict__ task_cursor, int* __restrict__ pair_base) {
    if (threadIdx.x == 0) {
        int acc = 0, pacc = 0;
        for (int t = 0; t < NTASK; ++t) {
            int c = task_count[t];
            task_start[t] = acc; task_cursor[t] = acc; acc += c;
            if (pair_base) {
                pair_base[t] = pacc;
                if (c >= 2 && c < BSZ) pacc += c * (c - 1);
            }
        }
    }
}

// ---------------- kernel 4: counting-sort scatter (+rank) ---------------------------
__global__ void k_scatter(const int* __restrict__ tasks, int* __restrict__ task_cursor,
                          const int* __restrict__ task_start,
                          int* __restrict__ sorted, int* __restrict__ rank_) {
    int i = blockIdx.x * 256 + threadIdx.x;
    if (i < BSZ) {
        int t = tasks[i];
        int pos = atomicAdd(&task_cursor[t], 1);
        sorted[pos] = i;
        if (rank_) rank_[i] = pos - task_start[t];
    }
}

// ---------------- kernel 5: neg_sum via bf16 MFMA + positive-sim scatter ------------
// Block = 256 thr (4 waves). Block tile 128(M)x128(N); wave tile 32x128.
// A/B fragment (16x16x32): lane holds row (lane&15), 8 contiguous k at (lane>>4)*8.
// C/D: col = lane&15, row = (lane>>4)*4 + reg  [guide m89 verified].
// Each (row,col) of the full matrix is produced exactly once -> plain store for pos.
__global__ __launch_bounds__(256) void k_negsum_store(
        const unsigned short* __restrict__ E,
        const int* __restrict__ tasks, const int* __restrict__ rank_,
        const int* __restrict__ task_count, const int* __restrict__ pair_base,
        float* __restrict__ neg_sum, float* __restrict__ posbuf) {
    const int nbn = BSZ / 128;           // 64
    int bn = blockIdx.x % nbn;
    int bm = blockIdx.x / nbn;
    int wave = threadIdx.x >> 6;
    int lane = threadIdx.x & 63;
    int g  = lane >> 4;                  // 0..3
    int lr = lane & 15;
    int m0 = bm * 128 + wave * 32;
    int n0 = bn * 128;

    f32x4 acc[2][8] = {};
    const unsigned short* arow0 = E + (size_t)(m0 + lr) * DIM      + g * 8;
    const unsigned short* arow1 = E + (size_t)(m0 + 16 + lr) * DIM + g * 8;

    #pragma unroll
    for (int ks = 0; ks < 8; ++ks) {
        int ko = ks * 32;
        bf16x8 a0 = *reinterpret_cast<const bf16x8*>(arow0 + ko);
        bf16x8 a1 = *reinterpret_cast<const bf16x8*>(arow1 + ko);
        #pragma unroll
        for (int f = 0; f < 8; ++f) {
            bf16x8 b = *reinterpret_cast<const bf16x8*>(E + (size_t)(n0 + f * 16 + lr) * DIM + g * 8 + ko);
            acc[0][f] = __builtin_amdgcn_mfma_f32_16x16x32_bf16(a0, b, acc[0][f], 0, 0, 0);
            acc[1][f] = __builtin_amdgcn_mfma_f32_16x16x32_bf16(a1, b, acc[1][f], 0, 0, 0);
        }
    }

    int colt[8], colrk[8];
    #pragma unroll
    for (int f = 0; f < 8; ++f) {
        int col = n0 + f * 16 + lr;
        colt[f]  = tasks[col];
        colrk[f] = rank_[col];
    }

    #pragma unroll
    for (int mi = 0; mi < 2; ++mi) {
        #pragma unroll
        for (int r = 0; r < 4; ++r) {
            int row = m0 + mi * 16 + g * 4 + r;
            int rt  = tasks[row];
            int rrk = rank_[row];
            int ct  = task_count[rt];
            int pb  = pair_base[rt];
            float s = 0.0f;
            #pragma unroll
            for (int f = 0; f < 8; ++f) {
                float sv = acc[mi][f][r] * INV_T;
                int col = n0 + f * 16 + lr;
                if (colt[f] != rt) {
                    s += __expf(sv);
                } else if (col != row && ct >= 2 && ct < BSZ) {
                    int cr  = colrk[f];
                    int idx = pb + rrk * (ct - 1) + cr - (cr > rrk ? 1 : 0);
                    if (idx < PAIR_CAP) posbuf[idx] = sv;
                }
            }
            s += __shfl_xor(s, 1); s += __shfl_xor(s, 2);
            s += __shfl_xor(s, 4); s += __shfl_xor(s, 8);
            if (lr == 0) atomicAdd(&neg_sum[row], s);
        }
    }
}

// ---------------- kernel 6: per-anchor positive-pair loss from stored sims ----------
__global__ __launch_bounds__(256) void k_pair(
        const int* __restrict__ sorted, const int* __restrict__ tasks,
        const int* __restrict__ rank_, const int* __restrict__ task_count,
        const int* __restrict__ pair_base, const float* __restrict__ neg_sum,
        const float* __restrict__ u, const float* __restrict__ posbuf,
        float* __restrict__ contr_sum) {
    int a    = blockIdx.x * 4 + (threadIdx.x >> 6);   // position in sorted order
    int lane = threadIdx.x & 63;
    int i = sorted[a];
    int t = tasks[i];
    int c = task_count[t];
    if (c < 2 || c >= BSZ) return;       // invalid anchor (no pos or no neg)
    int base = pair_base[t] + rank_[i] * (c - 1);
    float Ci = neg_sum[i] + 1e-8f;
    float local = 0.0f;
    for (int q = lane; q < c - 1; q += 64) {
        float sv = posbuf[base + q];
        local += logf(__expf(sv) + Ci) - sv;   // -log(exp(s)/(exp(s)+C))
    }
    #pragma unroll
    for (int s = 1; s < 64; s <<= 1) local += __shfl_xor(local, s);
    if (lane == 0) atomicAdd(contr_sum, u[i] * local);
}

// ---------------- fallback kernel: old per-pair recompute path ----------------------
__global__ __launch_bounds__(256) void k_pos(const unsigned short* __restrict__ E,
                                             const int* __restrict__ tasks,
                                             const int* __restrict__ sorted,
                                             const int* __restrict__ task_count,
                                             const int* __restrict__ task_start,
                                             const float* __restrict__ neg_sum,
                                             const float* __restrict__ u,
                                             float* __restrict__ contr_sum) {
    int p = blockIdx.x;
    int i = sorted[p];
    int t = tasks[i];
    int c = task_count[t];
    if (c < 2 || c >= BSZ) return;
    int st   = task_start[t];
    int wave = threadIdx.x >> 6;
    int lane = threadIdx.x & 63;
    ushort4 ei = *reinterpret_cast<const ushort4*>(E + (size_t)i * DIM + lane * 4);
    float e0 = bf2f(ei.x), e1 = bf2f(ei.y), e2 = bf2f(ei.z), e3 = bf2f(ei.w);
    float Ci = neg_sum[i] + 1e-8f;
    float local = 0.0f;
    for (int m = wave; m < c; m += 4) {
        int j = sorted[st + m];
        if (j == i) continue;
        ushort4 ej = *reinterpret_cast<const ushort4*>(E + (size_t)j * DIM + lane * 4);
        float d = e0 * bf2f(ej.x) + e1 * bf2f(ej.y) + e2 * bf2f(ej.z) + e3 * bf2f(ej.w);
        #pragma unroll
        for (int s = 1; s < 64; s <<= 1) d += __shfl_xor(d, s);
        float sv = d * INV_T;
        local += logf(__expf(sv) + Ci) - sv;
    }
    if (lane == 0) atomicAdd(contr_sum, u[i] * local);
}

// fallback negsum without pair storage
__global__ __launch_bounds__(256) void k_negsum(const unsigned short* __restrict__ E,
                                                const int* __restrict__ tasks,
                                                float* __restrict__ neg_sum) {
    const int nbn = BSZ / 128;
    int bn = blockIdx.x % nbn;
    int bm = blockIdx.x / nbn;
    int wave = threadIdx.x >> 6;
    int lane = threadIdx.x & 63;
    int g  = lane >> 4;
    int lr = lane & 15;
    int m0 = bm * 128 + wave * 32;
    int n0 = bn * 128;
    f32x4 acc[2][8] = {};
    const unsigned short* arow0 = E + (size_t)(m0 + lr) * DIM      + g * 8;
    const unsigned short* arow1 = E + (size_t)(m0 + 16 + lr) * DIM + g * 8;
    #pragma unroll
    for (int ks = 0; ks < 8; ++ks) {
        int ko = ks * 32;
        bf16x8 a0 = *reinterpret_cast<const bf16x8*>(arow0 + ko);
        bf16x8 a1 = *reinterpret_cast<const bf16x8*>(arow1 + ko);
        #pragma unroll
        for (int f = 0; f < 8; ++f) {
            bf16x8 b = *reinterpret_cast<const bf16x8*>(E + (size_t)(n0 + f * 16 + lr) * DIM + g * 8 + ko);
            acc[0][f] = __builtin_amdgcn_mfma_f32_16x16x32_bf16(a0, b, acc[0][f], 0, 0, 0);
            acc[1][f] = __builtin_amdgcn_mfma_f32_16x16x32_bf16(a1, b, acc[1][f], 0, 0, 0);
        }
    }
    int colt[8];
    #pragma unroll
    for (int f = 0; f < 8; ++f) colt[f] = tasks[n0 + f * 16 + lr];
    #pragma unroll
    for (int mi = 0; mi < 2; ++mi) {
        #pragma unroll
        for (int r = 0; r < 4; ++r) {
            int row = m0 + mi * 16 + g * 4 + r;
            int rt = tasks[row];
            float s = 0.0f;
            #pragma unroll
            for (int f = 0; f < 8; ++f) {
                float val = acc[mi][f][r] * INV_T;
                s += (colt[f] != rt) ? __expf(val) : 0.0f;
            }
            s += __shfl_xor(s, 1); s += __shfl_xor(s, 2);
            s += __shfl_xor(s, 4); s += __shfl_xor(s, 8);
            if (lr == 0) atomicAdd(&neg_sum[row], s);
        }
    }
}

// ---------------- kernel 7: final combine -------------------------------------------
__global__ void k_final(const int* __restrict__ task_count, const float* __restrict__ cls_sum,
                        const float* __restrict__ contr_sum, float* __restrict__ out) {
    int lane = threadIdx.x & 63;
    long long cnt = 0;
    if (lane < NTASK) {
        int c = task_count[lane];
        if (c >= 2 && c < BSZ) cnt = (long long)c * (c - 1);
    }
    #pragma unroll
    for (int s = 1; s < 64; s <<= 1) cnt += __shfl_xor(cnt, s);
    if (threadIdx.x == 0) {
        float cls = cls_sum[0] / (float)BSZ;
        float contr = (cnt > 0) ? (contr_sum[0] / (float)cnt) : 0.0f;
        out[0] = 0.7f * cls + 0.3f * contr;
    }
}

extern "C" void kernel_launch(void* const* d_in, const int* in_sizes, int n_in,
                              void* d_out, int out_size, void* d_ws, size_t ws_size,
                              hipStream_t stream) {
    const float* logits = (const float*)d_in[0];
    const float* emb    = (const float*)d_in[1];
    const int*   labels = (const int*)d_in[2];
    const int*   tasks  = (const int*)d_in[3];
    float* out = (float*)d_out;

    char* ws = (char*)d_ws;
    // layout (ints/floats are 4B):
    // header[512]: [0]=cls_sum [1]=contr_sum [64..]=task_count [128..]=task_start
    //              [192..]=task_cursor [256..]=pair_base
    // then neg_sum[BSZ], u[BSZ], sorted[BSZ], rank[BSZ], E bf16[BSZ*DIM], posbuf[PAIR_CAP]
    float* cls_sum     = (float*)ws;
    float* contr_sum   = cls_sum + 1;
    int*   task_count  = (int*)ws + 64;
    int*   task_start  = (int*)ws + 128;
    int*   task_cursor = (int*)ws + 192;
    int*   pair_base   = (int*)ws + 256;
    float* neg_sum     = (float*)ws + 512;
    float* u           = neg_sum + BSZ;
    int*   sorted      = (int*)ws + 512 + 2 * BSZ;
    int*   rank_       = (int*)ws + 512 + 3 * BSZ;
    unsigned short* e  = (unsigned short*)(ws + (size_t)(512 + 4 * BSZ) * 4);
    float* posbuf      = (float*)(ws + (size_t)(512 + 4 * BSZ) * 4 + (size_t)BSZ * DIM * 2);

    size_t need_full = (size_t)(512 + 4 * BSZ) * 4 + (size_t)BSZ * DIM * 2
                     + (size_t)PAIR_CAP * 4;
    bool fast = ws_size >= need_full;

    // zero accumulators + histogram + neg_sum every call (ws not re-poisoned)
    hipMemsetAsync(ws, 0, (size_t)(512 + BSZ) * 4, stream);

    k_prep   <<<BSZ / 4,  256, 0, stream>>>(logits, labels, tasks, u, cls_sum, task_count);
    k_norm   <<<BSZ / 4,  256, 0, stream>>>(emb, e);
    k_prefix <<<1,        64,  0, stream>>>(task_count, task_start, task_cursor,
                                            fast ? pair_base : nullptr);
    k_scatter<<<BSZ / 256,256, 0, stream>>>(tasks, task_cursor, task_start, sorted,
                                            fast ? rank_ : nullptr);
    if (fast) {
        k_negsum_store<<<4096, 256, 0, stream>>>(e, tasks, rank_, task_count, pair_base,
                                                 neg_sum, posbuf);
        k_pair  <<<BSZ / 4, 256, 0, stream>>>(sorted, tasks, rank_, task_count, pair_base,
                                              neg_sum, u, posbuf, contr_sum);
    } else {
        k_negsum<<<4096,    256, 0, stream>>>(e, tasks, neg_sum);
        k_pos   <<<BSZ,     256, 0, stream>>>(e, tasks, sorted, task_count, task_start,
                                              neg_sum, u, contr_sum);
    }
    k_final  <<<1,        64,  0, stream>>>(task_count, cls_sum, contr_sum, out);
}

// Round 3
// 186.122 us; speedup vs baseline: 4.2864x; 2.5372x over previous
//
#include <hip/hip_runtime.h>
#include <hip/hip_bf16.h>
#include <math.h>

#define BSZ   8192
#define NCLS  57
#define DIM   256
#define NTASK 57
#define INV_T (1.0f/0.07f)
#define PAIR_CAP (2*1024*1024)   // 2M pairs (actual ~1.17M)
#define BM 128
#define BN 128
#define BKE 64                   // K elements per LDS stage step

typedef short bf16x8 __attribute__((ext_vector_type(8)));
typedef float f32x4  __attribute__((ext_vector_type(4)));

__device__ __forceinline__ float bf2f(unsigned short h) {
    return __uint_as_float(((unsigned int)h) << 16);
}

// async global->LDS, 16B per lane; l must be wave-uniform base (HW adds lane*16)
__device__ __forceinline__ void gload_lds16(const void* g, void* l) {
    __builtin_amdgcn_global_load_lds(
        (const __attribute__((address_space(1))) unsigned int*)g,
        (__attribute__((address_space(3))) unsigned int*)l, 16, 0, 0);
}

// ---- kernel 1: fused logits stats (cls loss, uncertainty, histogram) + normalize ---
__global__ __launch_bounds__(256) void k_prep(
        const float* __restrict__ logits, const float* __restrict__ emb,
        const int* __restrict__ labels, const int* __restrict__ tasks,
        float* __restrict__ u, float* __restrict__ cls_part,
        int* __restrict__ task_count, unsigned short* __restrict__ e) {
    __shared__ float scls[4];
    int wave = threadIdx.x >> 6;
    int lane = threadIdx.x & 63;
    int row  = blockIdx.x * 4 + wave;

    // --- logits: softmax stats ---
    float v = (lane < NCLS) ? logits[row * NCLS + lane] : -3.0e38f;
    float m = v;
    #pragma unroll
    for (int s = 1; s < 64; s <<= 1) m = fmaxf(m, __shfl_xor(m, s));
    float ex = (lane < NCLS) ? __expf(v - m) : 0.0f;
    float se = ex;
    #pragma unroll
    for (int s = 1; s < 64; s <<= 1) se += __shfl_xor(se, s);
    float lse = m + logf(se);
    float p = ex / se;
    float term = (lane < NCLS) ? p * logf(p + 1e-8f) : 0.0f;
    float ent = term;
    #pragma unroll
    for (int s = 1; s < 64; s <<= 1) ent += __shfl_xor(ent, s);
    ent = -ent;
    int lab = labels[row];
    float vl = __shfl(v, lab);           // logits[row][label]
    float cls = lse - vl;                // -log_softmax[label]

    // --- embeddings: L2-normalize -> bf16 ---
    const float4* src = reinterpret_cast<const float4*>(emb + (size_t)row * DIM);
    float4 x = src[lane];
    float ss = x.x*x.x + x.y*x.y + x.z*x.z + x.w*x.w;
    #pragma unroll
    for (int s = 1; s < 64; s <<= 1) ss += __shfl_xor(ss, s);
    float sc = 1.0f / fmaxf(sqrtf(ss), 1e-12f);
    ushort4 o;
    __hip_bfloat16 b0 = __float2bfloat16(x.x * sc);
    __hip_bfloat16 b1 = __float2bfloat16(x.y * sc);
    __hip_bfloat16 b2 = __float2bfloat16(x.z * sc);
    __hip_bfloat16 b3 = __float2bfloat16(x.w * sc);
    o.x = *reinterpret_cast<unsigned short*>(&b0);
    o.y = *reinterpret_cast<unsigned short*>(&b1);
    o.z = *reinterpret_cast<unsigned short*>(&b2);
    o.w = *reinterpret_cast<unsigned short*>(&b3);
    *reinterpret_cast<ushort4*>(e + (size_t)row * DIM + lane * 4) = o;

    // --- per-block cls partial (avoid 8192-way single-address atomic) ---
    if (lane == 0) {
        u[row] = ent / 4.04305127f;      // log(57)
        atomicAdd(&task_count[tasks[row]], 1);   // 57 addresses: fine
        scls[wave] = cls;
    }
    __syncthreads();
    if (threadIdx.x == 0) cls_part[blockIdx.x] = scls[0] + scls[1] + scls[2] + scls[3];
}

// ---- kernel 2: wave-parallel exclusive prefix scans --------------------------------
__global__ void k_prefix(const int* __restrict__ task_count, int* __restrict__ task_start,
                         int* __restrict__ task_cursor, int* __restrict__ pair_base) {
    int lane = threadIdx.x & 63;
    int c = (lane < NTASK) ? task_count[lane] : 0;
    int p = (lane < NTASK && c >= 2 && c < BSZ) ? c * (c - 1) : 0;
    int xc = c, xp = p;
    #pragma unroll
    for (int s = 1; s < 64; s <<= 1) {
        int yc = __shfl_up(xc, s), yp = __shfl_up(xp, s);
        if (lane >= s) { xc += yc; xp += yp; }
    }
    if (lane < NTASK) {
        task_start[lane]  = xc - c;
        task_cursor[lane] = xc - c;
        pair_base[lane]   = xp - p;
    }
}

// ---- kernel 3: counting-sort scatter (+rank) ---------------------------------------
__global__ void k_scatter(const int* __restrict__ tasks, int* __restrict__ task_cursor,
                          const int* __restrict__ task_start,
                          int* __restrict__ sorted, int* __restrict__ rank_) {
    int i = blockIdx.x * 256 + threadIdx.x;
    if (i < BSZ) {
        int t = tasks[i];
        int pos = atomicAdd(&task_cursor[t], 1);
        sorted[pos] = i;
        rank_[i] = pos - task_start[t];
    }
}

// ---- kernel 4: sim matrix via MFMA w/ LDS staging; neg_sum + pos-sim scatter -------
// m97 structure: 128x128 block tile, BK=64, global_load_lds 16B, single-buffered,
// 2 barriers per K-step. Linear LDS (T2 swizzle is NULL in 2-phase regime).
// Wave tile 32x128. A/B frag (16x16x32): row=lane&15, 8 contig k at (lane>>4)*8.
// C/D: col=lane&15, row=(lane>>4)*4+reg.
__global__ __launch_bounds__(256) void k_negsum_store(
        const unsigned short* __restrict__ E,
        const int* __restrict__ tasks, const int* __restrict__ rank_,
        const int* __restrict__ task_count, const int* __restrict__ pair_base,
        float* __restrict__ neg_sum, float* __restrict__ posbuf) {
    __shared__ unsigned short As[BM][BKE];   // 16 KB
    __shared__ unsigned short Bs[BN][BKE];   // 16 KB
    const int nbn = BSZ / BN;                // 64
    // XCD-aware swizzle (nwg=4096, divisible by 8 -> bijective)
    int bid = blockIdx.x;
    bid = (bid & 7) * (4096 / 8) + (bid >> 3);
    int bn = bid % nbn;
    int bm = bid / nbn;
    int wave = threadIdx.x >> 6;
    int lane = threadIdx.x & 63;
    int tid  = threadIdx.x;
    int g  = lane >> 4;                      // 0..3
    int lr = lane & 15;
    int m0 = bm * BM;
    int n0 = bn * BN;

    f32x4 acc[2][8] = {};

    for (int kk = 0; kk < DIM / BKE; ++kk) {
        __syncthreads();                     // prev compute done before overwrite
        #pragma unroll
        for (int l = 0; l < 4; ++l) {
            int flat = l * 256 + tid;        // 16B chunk index
            int row = flat >> 3, kb = flat & 7;
            const unsigned short* ga = E + (size_t)(m0 + row) * DIM + kk * BKE + kb * 8;
            const unsigned short* gb = E + (size_t)(n0 + row) * DIM + kk * BKE + kb * 8;
            unsigned short* la = &As[0][0] + (size_t)(l * 256 + wave * 64) * 8;  // wave-uniform
            unsigned short* lb = &Bs[0][0] + (size_t)(l * 256 + wave * 64) * 8;
            gload_lds16(ga, la);
            gload_lds16(gb, lb);
        }
        __syncthreads();                     // drains vmcnt(0) before ds_read
        #pragma unroll
        for (int ks = 0; ks < 2; ++ks) {
            bf16x8 a0 = *reinterpret_cast<const bf16x8*>(&As[wave * 32 + lr][ks * 32 + g * 8]);
            bf16x8 a1 = *reinterpret_cast<const bf16x8*>(&As[wave * 32 + 16 + lr][ks * 32 + g * 8]);
            #pragma unroll
            for (int f = 0; f < 8; ++f) {
                bf16x8 b = *reinterpret_cast<const bf16x8*>(&Bs[f * 16 + lr][ks * 32 + g * 8]);
                acc[0][f] = __builtin_amdgcn_mfma_f32_16x16x32_bf16(a0, b, acc[0][f], 0, 0, 0);
                acc[1][f] = __builtin_amdgcn_mfma_f32_16x16x32_bf16(a1, b, acc[1][f], 0, 0, 0);
            }
        }
    }

    // ---- epilogue: exp-sum negatives per row + scatter positive sims ----
    int colt[8], colrk[8];
    #pragma unroll
    for (int f = 0; f < 8; ++f) {
        int col = n0 + f * 16 + lr;
        colt[f]  = tasks[col];
        colrk[f] = rank_[col];
    }
    #pragma unroll
    for (int mi = 0; mi < 2; ++mi) {
        #pragma unroll
        for (int r = 0; r < 4; ++r) {
            int row = m0 + wave * 32 + mi * 16 + g * 4 + r;
            int rt  = tasks[row];
            int rrk = rank_[row];
            int ct  = task_count[rt];
            int pb  = pair_base[rt];
            float s = 0.0f;
            #pragma unroll
            for (int f = 0; f < 8; ++f) {
                float sv = acc[mi][f][r] * INV_T;
                int col = n0 + f * 16 + lr;
                if (colt[f] != rt) {
                    s += __expf(sv);
                } else if (col != row && ct >= 2 && ct < BSZ) {
                    int cr  = colrk[f];
                    int idx = pb + rrk * (ct - 1) + cr - (cr > rrk ? 1 : 0);
                    if (idx < PAIR_CAP) posbuf[idx] = sv;   // exactly-once writer
                }
            }
            s += __shfl_xor(s, 1); s += __shfl_xor(s, 2);
            s += __shfl_xor(s, 4); s += __shfl_xor(s, 8);
            if (lr == 0) atomicAdd(&neg_sum[row], s);       // 64 adds/row: fine
        }
    }
}

// ---- kernel 5: per-anchor positive-pair loss from stored sims ----------------------
__global__ __launch_bounds__(256) void k_pair(
        const int* __restrict__ sorted, const int* __restrict__ tasks,
        const int* __restrict__ rank_, const int* __restrict__ task_count,
        const int* __restrict__ pair_base, const float* __restrict__ neg_sum,
        const float* __restrict__ u, const float* __restrict__ posbuf,
        float* __restrict__ contr_part) {
    __shared__ float sp[4];
    int wave = threadIdx.x >> 6;
    int lane = threadIdx.x & 63;
    int a = blockIdx.x * 4 + wave;           // position in sorted order
    float wsum = 0.0f;
    int i = sorted[a];
    int t = tasks[i];
    int c = task_count[t];
    if (c >= 2 && c < BSZ) {
        int base = pair_base[t] + rank_[i] * (c - 1);
        float Ci = neg_sum[i] + 1e-8f;
        float local = 0.0f;
        for (int q = lane; q < c - 1; q += 64) {
            float sv = posbuf[base + q];
            local += logf(__expf(sv) + Ci) - sv;   // -log(exp(s)/(exp(s)+C))
        }
        #pragma unroll
        for (int s = 1; s < 64; s <<= 1) local += __shfl_xor(local, s);
        wsum = u[i] * local;
    }
    if (lane == 0) sp[wave] = wsum;
    __syncthreads();
    if (threadIdx.x == 0) contr_part[blockIdx.x] = sp[0] + sp[1] + sp[2] + sp[3];
}

// ---- kernel 6: final reduce + combine ----------------------------------------------
__global__ __launch_bounds__(256) void k_final(
        const int* __restrict__ task_count, const float* __restrict__ cls_part,
        const float* __restrict__ contr_part, float* __restrict__ out) {
    __shared__ float sc[4], sp[4];
    int tid = threadIdx.x, wave = tid >> 6, lane = tid & 63;
    float c1 = 0.0f, c2 = 0.0f;
    for (int i = tid; i < BSZ / 4; i += 256) { c1 += cls_part[i]; c2 += contr_part[i]; }
    #pragma unroll
    for (int s = 1; s < 64; s <<= 1) { c1 += __shfl_xor(c1, s); c2 += __shfl_xor(c2, s); }
    if (lane == 0) { sc[wave] = c1; sp[wave] = c2; }
    long long cnt = 0;
    if (tid < 64) {
        int c = (lane < NTASK) ? task_count[lane] : 0;
        cnt = (c >= 2 && c < BSZ) ? (long long)c * (c - 1) : 0;
        #pragma unroll
        for (int s = 1; s < 64; s <<= 1) cnt += __shfl_xor(cnt, s);
    }
    __syncthreads();
    if (tid == 0) {
        float cls = (sc[0] + sc[1] + sc[2] + sc[3]) / (float)BSZ;
        float con = sp[0] + sp[1] + sp[2] + sp[3];
        out[0] = 0.7f * cls + 0.3f * (cnt > 0 ? con / (float)cnt : 0.0f);
    }
}

extern "C" void kernel_launch(void* const* d_in, const int* in_sizes, int n_in,
                              void* d_out, int out_size, void* d_ws, size_t ws_size,
                              hipStream_t stream) {
    const float* logits = (const float*)d_in[0];
    const float* emb    = (const float*)d_in[1];
    const int*   labels = (const int*)d_in[2];
    const int*   tasks  = (const int*)d_in[3];
    float* out = (float*)d_out;

    char* ws = (char*)d_ws;
    // layout (4B units):
    // header[512]: [64..]=task_count [128..]=task_start [192..]=task_cursor [256..]=pair_base
    // neg_sum[BSZ], u[BSZ], sorted[BSZ], rank[BSZ], cls_part[2048], contr_part[2048],
    // E bf16[BSZ*DIM], posbuf[PAIR_CAP]
    int*   task_count  = (int*)ws + 64;
    int*   task_start  = (int*)ws + 128;
    int*   task_cursor = (int*)ws + 192;
    int*   pair_base   = (int*)ws + 256;
    float* neg_sum     = (float*)ws + 512;
    float* u           = neg_sum + BSZ;
    int*   sorted      = (int*)ws + 512 + 2 * BSZ;
    int*   rank_       = (int*)ws + 512 + 3 * BSZ;
    float* cls_part    = (float*)ws + 512 + 4 * BSZ;
    float* contr_part  = cls_part + 2048;
    unsigned short* e  = (unsigned short*)(ws + (size_t)(512 + 4 * BSZ + 4096) * 4);
    float* posbuf      = (float*)((char*)e + (size_t)BSZ * DIM * 2);

    // zero header (task_count) + neg_sum every call (ws not re-poisoned between replays;
    // cls_part/contr_part/posbuf/u/sorted/rank are fully overwritten each call)
    hipMemsetAsync(ws, 0, (size_t)(512 + BSZ) * 4, stream);

    k_prep   <<<BSZ / 4,   256, 0, stream>>>(logits, emb, labels, tasks, u, cls_part,
                                             task_count, e);
    k_prefix <<<1,         64,  0, stream>>>(task_count, task_start, task_cursor, pair_base);
    k_scatter<<<BSZ / 256, 256, 0, stream>>>(tasks, task_cursor, task_start, sorted, rank_);
    k_negsum_store<<<4096, 256, 0, stream>>>(e, tasks, rank_, task_count, pair_base,
                                             neg_sum, posbuf);
    k_pair   <<<BSZ / 4,   256, 0, stream>>>(sorted, tasks, rank_, task_count, pair_base,
                                             neg_sum, u, posbuf, contr_part);
    k_final  <<<1,         256, 0, stream>>>(task_count, cls_part, contr_part, out);
}

// Round 4
// 170.200 us; speedup vs baseline: 4.6873x; 1.0935x over previous
//
#include <hip/hip_runtime.h>
#include <hip/hip_bf16.h>
#include <math.h>

#define BSZ   8192
#define NCLS  57
#define DIM   256
#define NTASK 57
#define INV_T (1.0f/0.07f)
#define PAIR_CAP (2*1024*1024)   // 2M pairs (actual ~1.17M)
#define BM 128
#define BN 128
#define BKE 64                   // K elements per LDS stage step
#define NBN (BSZ / BN)           // 64
#define NTRI (NBN * (NBN + 1) / 2)   // 2080 lower-triangle tiles

typedef short bf16x8 __attribute__((ext_vector_type(8)));
typedef float f32x4  __attribute__((ext_vector_type(4)));

// async global->LDS, 16B per lane; l must be wave-uniform base (HW adds lane*16)
__device__ __forceinline__ void gload_lds16(const void* g, void* l) {
    __builtin_amdgcn_global_load_lds(
        (const __attribute__((address_space(1))) unsigned int*)g,
        (__attribute__((address_space(3))) unsigned int*)l, 16, 0, 0);
}

// ---- kernel 1: fused logits stats + normalize + neg_sum zeroing --------------------
__global__ __launch_bounds__(256) void k_prep(
        const float* __restrict__ logits, const float* __restrict__ emb,
        const int* __restrict__ labels, const int* __restrict__ tasks,
        float* __restrict__ u, float* __restrict__ cls_part,
        int* __restrict__ task_count, unsigned short* __restrict__ e,
        float* __restrict__ neg_sum) {
    __shared__ float scls[4];
    int wave = threadIdx.x >> 6;
    int lane = threadIdx.x & 63;
    int row  = blockIdx.x * 4 + wave;

    // --- logits: softmax stats ---
    float v = (lane < NCLS) ? logits[row * NCLS + lane] : -3.0e38f;
    float m = v;
    #pragma unroll
    for (int s = 1; s < 64; s <<= 1) m = fmaxf(m, __shfl_xor(m, s));
    float ex = (lane < NCLS) ? __expf(v - m) : 0.0f;
    float se = ex;
    #pragma unroll
    for (int s = 1; s < 64; s <<= 1) se += __shfl_xor(se, s);
    float lse = m + logf(se);
    float p = ex / se;
    float term = (lane < NCLS) ? p * logf(p + 1e-8f) : 0.0f;
    float ent = term;
    #pragma unroll
    for (int s = 1; s < 64; s <<= 1) ent += __shfl_xor(ent, s);
    ent = -ent;
    int lab = labels[row];
    float vl = __shfl(v, lab);           // logits[row][label]
    float cls = lse - vl;                // -log_softmax[label]

    // --- embeddings: L2-normalize -> bf16 ---
    const float4* src = reinterpret_cast<const float4*>(emb + (size_t)row * DIM);
    float4 x = src[lane];
    float ss = x.x*x.x + x.y*x.y + x.z*x.z + x.w*x.w;
    #pragma unroll
    for (int s = 1; s < 64; s <<= 1) ss += __shfl_xor(ss, s);
    float sc = 1.0f / fmaxf(sqrtf(ss), 1e-12f);
    ushort4 o;
    __hip_bfloat16 b0 = __float2bfloat16(x.x * sc);
    __hip_bfloat16 b1 = __float2bfloat16(x.y * sc);
    __hip_bfloat16 b2 = __float2bfloat16(x.z * sc);
    __hip_bfloat16 b3 = __float2bfloat16(x.w * sc);
    o.x = *reinterpret_cast<unsigned short*>(&b0);
    o.y = *reinterpret_cast<unsigned short*>(&b1);
    o.z = *reinterpret_cast<unsigned short*>(&b2);
    o.w = *reinterpret_cast<unsigned short*>(&b3);
    *reinterpret_cast<ushort4*>(e + (size_t)row * DIM + lane * 4) = o;

    if (lane == 0) {
        u[row] = ent / 4.04305127f;      // log(57)
        neg_sum[row] = 0.0f;             // zero before k_negsum (next grid)
        atomicAdd(&task_count[tasks[row]], 1);   // 57 addresses: fine
        scls[wave] = cls;
    }
    __syncthreads();
    if (threadIdx.x == 0) cls_part[blockIdx.x] = scls[0] + scls[1] + scls[2] + scls[3];
}

// ---- kernel 2: wave-parallel exclusive prefix scans --------------------------------
__global__ void k_prefix(const int* __restrict__ task_count, int* __restrict__ task_start,
                         int* __restrict__ task_cursor, int* __restrict__ pair_base) {
    int lane = threadIdx.x & 63;
    int c = (lane < NTASK) ? task_count[lane] : 0;
    int p = (lane < NTASK && c >= 2 && c < BSZ) ? c * (c - 1) : 0;
    int xc = c, xp = p;
    #pragma unroll
    for (int s = 1; s < 64; s <<= 1) {
        int yc = __shfl_up(xc, s), yp = __shfl_up(xp, s);
        if (lane >= s) { xc += yc; xp += yp; }
    }
    if (lane < NTASK) {
        task_start[lane]  = xc - c;
        task_cursor[lane] = xc - c;
        pair_base[lane]   = xp - p;
    }
}

// ---- kernel 3: counting-sort scatter (+rank) ---------------------------------------
__global__ void k_scatter(const int* __restrict__ tasks, int* __restrict__ task_cursor,
                          const int* __restrict__ task_start,
                          int* __restrict__ sorted, int* __restrict__ rank_) {
    int i = blockIdx.x * 256 + threadIdx.x;
    if (i < BSZ) {
        int t = tasks[i];
        int pos = atomicAdd(&task_cursor[t], 1);
        sorted[pos] = i;
        rank_[i] = pos - task_start[t];
    }
}

// ---- kernel 4: sim matrix, LOWER TRIANGLE ONLY (sim is symmetric) ------------------
// 128x128 tiles, BK=64, global_load_lds 16B, single-buffered 2-phase.
// LDS XOR-swizzle (rule #21): linear LDS dest, pre-swizzled GLOBAL source chunk
// (kb ^= row&7), same XOR on the ds_read chunk -> 16-way conflict becomes 2-way(free).
// Off-diagonal tiles: each exp(s_ij) feeds neg_sum[i] (row-reduce) AND neg_sum[j]
// (col-reduce via shfl_xor 16/32); same-task elements store BOTH posbuf orientations.
__global__ __launch_bounds__(256) void k_negsum_store(
        const unsigned short* __restrict__ E,
        const int* __restrict__ tasks, const int* __restrict__ rank_,
        const int* __restrict__ task_count, const int* __restrict__ pair_base,
        float* __restrict__ neg_sum, float* __restrict__ posbuf) {
    __shared__ unsigned short As[BM][BKE];   // 16 KB
    __shared__ unsigned short Bs[BN][BKE];   // 16 KB

    // XCD-aware swizzle (NTRI=2080 divisible by 8 -> bijective)
    int b = (blockIdx.x & 7) * (NTRI / 8) + (blockIdx.x >> 3);
    // decode lower triangle: b = bn*(bn+1)/2 + bm, bm <= bn
    int bn = (int)((sqrtf(8.0f * (float)b + 1.0f) - 1.0f) * 0.5f);
    while ((bn + 1) * (bn + 2) / 2 <= b) ++bn;
    while (bn * (bn + 1) / 2 > b) --bn;
    int bm = b - bn * (bn + 1) / 2;
    bool diag = (bm == bn);

    int wave = threadIdx.x >> 6;
    int lane = threadIdx.x & 63;
    int tid  = threadIdx.x;
    int g  = lane >> 4;                      // 0..3
    int lr = lane & 15;
    int m0 = bm * BM;                        // rows (A)
    int n0 = bn * BN;                        // cols (B)
    int sw = lr & 7;                         // read-side XOR (row&7 == lr&7 here)

    f32x4 acc[2][8] = {};

    for (int kk = 0; kk < DIM / BKE; ++kk) {
        __syncthreads();                     // prev compute done before overwrite
        #pragma unroll
        for (int l = 0; l < 4; ++l) {
            int flat = l * 256 + tid;        // 16B chunk index (linear LDS dest)
            int row = flat >> 3, kb = flat & 7;
            int kbs = kb ^ (row & 7);        // pre-swizzled global source chunk
            const unsigned short* ga = E + (size_t)(m0 + row) * DIM + kk * BKE + kbs * 8;
            const unsigned short* gb = E + (size_t)(n0 + row) * DIM + kk * BKE + kbs * 8;
            unsigned short* la = &As[0][0] + (size_t)(l * 256 + wave * 64) * 8;  // wave-uniform
            unsigned short* lb = &Bs[0][0] + (size_t)(l * 256 + wave * 64) * 8;
            gload_lds16(ga, la);
            gload_lds16(gb, lb);
        }
        __syncthreads();                     // drains vmcnt(0) before ds_read
        #pragma unroll
        for (int ks = 0; ks < 2; ++ks) {
            int c = ks * 4 + g;              // wanted global chunk
            int cs = (c ^ sw) * 8;           // swizzled LDS offset (elements)
            bf16x8 a0 = *reinterpret_cast<const bf16x8*>(&As[wave * 32 + lr][cs]);
            bf16x8 a1 = *reinterpret_cast<const bf16x8*>(&As[wave * 32 + 16 + lr][cs]);
            #pragma unroll
            for (int f = 0; f < 8; ++f) {
                bf16x8 bfr = *reinterpret_cast<const bf16x8*>(&Bs[f * 16 + lr][cs]);
                acc[0][f] = __builtin_amdgcn_mfma_f32_16x16x32_bf16(a0, bfr, acc[0][f], 0, 0, 0);
                acc[1][f] = __builtin_amdgcn_mfma_f32_16x16x32_bf16(a1, bfr, acc[1][f], 0, 0, 0);
            }
        }
    }

    // ---- epilogue ----
    int colt[8], colrk[8];
    #pragma unroll
    for (int f = 0; f < 8; ++f) {
        int col = n0 + f * 16 + lr;
        colt[f]  = tasks[col];
        colrk[f] = rank_[col];
    }
    float csum[8] = {};                      // col-direction exp partials (off-diag)

    #pragma unroll
    for (int mi = 0; mi < 2; ++mi) {
        #pragma unroll
        for (int r = 0; r < 4; ++r) {
            int row = m0 + wave * 32 + mi * 16 + g * 4 + r;
            int rt  = tasks[row];
            int rrk = rank_[row];
            int ct  = task_count[rt];
            int pb  = pair_base[rt];
            bool vt = (ct >= 2 && ct < BSZ);
            float s = 0.0f;
            #pragma unroll
            for (int f = 0; f < 8; ++f) {
                float sv = acc[mi][f][r] * INV_T;
                int col = n0 + f * 16 + lr;
                if (colt[f] != rt) {
                    float ev = __expf(sv);
                    s += ev;                               // -> neg_sum[row]
                    csum[f] += ev;                         // -> neg_sum[col] (off-diag)
                } else if (col != row && vt) {
                    int cr = colrk[f];
                    int idx = pb + rrk * (ct - 1) + cr - (cr > rrk ? 1 : 0);
                    if (idx < PAIR_CAP) posbuf[idx] = sv;  // (i,j)
                    if (!diag) {
                        int jdx = pb + cr * (ct - 1) + rrk - (rrk > cr ? 1 : 0);
                        if (jdx < PAIR_CAP) posbuf[jdx] = sv;  // (j,i) via symmetry
                    }
                }
            }
            s += __shfl_xor(s, 1); s += __shfl_xor(s, 2);
            s += __shfl_xor(s, 4); s += __shfl_xor(s, 8);
            if (lr == 0) atomicAdd(&neg_sum[row], s);
        }
    }
    if (!diag) {
        #pragma unroll
        for (int f = 0; f < 8; ++f) {
            float cs = csum[f];
            cs += __shfl_xor(cs, 16); cs += __shfl_xor(cs, 32);
            if (g == 0) atomicAdd(&neg_sum[n0 + f * 16 + lr], cs);
        }
    }
}

// ---- kernel 5: per-anchor positive-pair loss from stored sims ----------------------
__global__ __launch_bounds__(256) void k_pair(
        const int* __restrict__ sorted, const int* __restrict__ tasks,
        const int* __restrict__ rank_, const int* __restrict__ task_count,
        const int* __restrict__ pair_base, const float* __restrict__ neg_sum,
        const float* __restrict__ u, const float* __restrict__ posbuf,
        float* __restrict__ contr_part) {
    __shared__ float sp[4];
    int wave = threadIdx.x >> 6;
    int lane = threadIdx.x & 63;
    int a = blockIdx.x * 4 + wave;           // position in sorted order
    float wsum = 0.0f;
    int i = sorted[a];
    int t = tasks[i];
    int c = task_count[t];
    if (c >= 2 && c < BSZ) {
        int base = pair_base[t] + rank_[i] * (c - 1);
        float Ci = neg_sum[i] + 1e-8f;
        float local = 0.0f;
        for (int q = lane; q < c - 1; q += 64) {
            float sv = posbuf[base + q];
            local += logf(__expf(sv) + Ci) - sv;   // -log(exp(s)/(exp(s)+C))
        }
        #pragma unroll
        for (int s = 1; s < 64; s <<= 1) local += __shfl_xor(local, s);
        wsum = u[i] * local;
    }
    if (lane == 0) sp[wave] = wsum;
    __syncthreads();
    if (threadIdx.x == 0) contr_part[blockIdx.x] = sp[0] + sp[1] + sp[2] + sp[3];
}

// ---- kernel 6: final reduce + combine ----------------------------------------------
__global__ __launch_bounds__(256) void k_final(
        const int* __restrict__ task_count, const float* __restrict__ cls_part,
        const float* __restrict__ contr_part, float* __restrict__ out) {
    __shared__ float sc[4], sp[4];
    int tid = threadIdx.x, wave = tid >> 6, lane = tid & 63;
    float c1 = 0.0f, c2 = 0.0f;
    for (int i = tid; i < BSZ / 4; i += 256) { c1 += cls_part[i]; c2 += contr_part[i]; }
    #pragma unroll
    for (int s = 1; s < 64; s <<= 1) { c1 += __shfl_xor(c1, s); c2 += __shfl_xor(c2, s); }
    if (lane == 0) { sc[wave] = c1; sp[wave] = c2; }
    long long cnt = 0;
    if (tid < 64) {
        int c = (lane < NTASK) ? task_count[lane] : 0;
        cnt = (c >= 2 && c < BSZ) ? (long long)c * (c - 1) : 0;
        #pragma unroll
        for (int s = 1; s < 64; s <<= 1) cnt += __shfl_xor(cnt, s);
    }
    __syncthreads();
    if (tid == 0) {
        float cls = (sc[0] + sc[1] + sc[2] + sc[3]) / (float)BSZ;
        float con = sp[0] + sp[1] + sp[2] + sp[3];
        out[0] = 0.7f * cls + 0.3f * (cnt > 0 ? con / (float)cnt : 0.0f);
    }
}

extern "C" void kernel_launch(void* const* d_in, const int* in_sizes, int n_in,
                              void* d_out, int out_size, void* d_ws, size_t ws_size,
                              hipStream_t stream) {
    const float* logits = (const float*)d_in[0];
    const float* emb    = (const float*)d_in[1];
    const int*   labels = (const int*)d_in[2];
    const int*   tasks  = (const int*)d_in[3];
    float* out = (float*)d_out;

    char* ws = (char*)d_ws;
    // layout (4B units):
    // header[512]: [64..]=task_count [128..]=task_start [192..]=task_cursor [256..]=pair_base
    // neg_sum[BSZ], u[BSZ], sorted[BSZ], rank[BSZ], cls_part[2048], contr_part[2048],
    // E bf16[BSZ*DIM], posbuf[PAIR_CAP]
    int*   task_count  = (int*)ws + 64;
    int*   task_start  = (int*)ws + 128;
    int*   task_cursor = (int*)ws + 192;
    int*   pair_base   = (int*)ws + 256;
    float* neg_sum     = (float*)ws + 512;
    float* u           = neg_sum + BSZ;
    int*   sorted      = (int*)ws + 512 + 2 * BSZ;
    int*   rank_       = (int*)ws + 512 + 3 * BSZ;
    float* cls_part    = (float*)ws + 512 + 4 * BSZ;
    float* contr_part  = cls_part + 2048;
    unsigned short* e  = (unsigned short*)(ws + (size_t)(512 + 4 * BSZ + 4096) * 4);
    float* posbuf      = (float*)((char*)e + (size_t)BSZ * DIM * 2);

    // zero header only (task_count); neg_sum zeroed inside k_prep
    hipMemsetAsync(ws, 0, 512 * 4, stream);

    k_prep   <<<BSZ / 4,   256, 0, stream>>>(logits, emb, labels, tasks, u, cls_part,
                                             task_count, e, neg_sum);
    k_prefix <<<1,         64,  0, stream>>>(task_count, task_start, task_cursor, pair_base);
    k_scatter<<<BSZ / 256, 256, 0, stream>>>(tasks, task_cursor, task_start, sorted, rank_);
    k_negsum_store<<<NTRI, 256, 0, stream>>>(e, tasks, rank_, task_count, pair_base,
                                             neg_sum, posbuf);
    k_pair   <<<BSZ / 4,   256, 0, stream>>>(sorted, tasks, rank_, task_count, pair_base,
                                             neg_sum, u, posbuf, contr_part);
    k_final  <<<1,         256, 0, stream>>>(task_count, cls_part, contr_part, out);
}

// Round 5
// 148.847 us; speedup vs baseline: 5.3598x; 1.1435x over previous
//
#include <hip/hip_runtime.h>
#include <hip/hip_bf16.h>
#include <math.h>

#define BSZ   8192
#define NCLS  57
#define DIM   256
#define NTASK 57
#define INV_T (1.0f/0.07f)
#define PAIR_CAP (2*1024*1024)   // 2M pairs (actual ~1.17M)
#define BM 128
#define BN 128
#define BKE 64                   // K elements per LDS stage step
#define NBN (BSZ / BN)           // 64
#define NTRI (NBN * (NBN + 1) / 2)   // 2080 lower-triangle tiles

typedef short bf16x8 __attribute__((ext_vector_type(8)));
typedef float f32x4  __attribute__((ext_vector_type(4)));

// async global->LDS, 16B per lane; l must be wave-uniform base (HW adds lane*16)
__device__ __forceinline__ void gload_lds16(const void* g, void* l) {
    __builtin_amdgcn_global_load_lds(
        (const __attribute__((address_space(1))) unsigned int*)g,
        (__attribute__((address_space(3))) unsigned int*)l, 16, 0, 0);
}

// ---- kernel 1: fused logits stats + normalize + neg_sum zeroing --------------------
__global__ __launch_bounds__(256) void k_prep(
        const float* __restrict__ logits, const float* __restrict__ emb,
        const int* __restrict__ labels, const int* __restrict__ tasks,
        float* __restrict__ u, float* __restrict__ cls_part,
        int* __restrict__ task_count, unsigned short* __restrict__ e,
        float* __restrict__ neg_sum) {
    __shared__ float scls[4];
    int wave = threadIdx.x >> 6;
    int lane = threadIdx.x & 63;
    int row  = blockIdx.x * 4 + wave;

    // --- logits: softmax stats ---
    float v = (lane < NCLS) ? logits[row * NCLS + lane] : -3.0e38f;
    float m = v;
    #pragma unroll
    for (int s = 1; s < 64; s <<= 1) m = fmaxf(m, __shfl_xor(m, s));
    float ex = (lane < NCLS) ? __expf(v - m) : 0.0f;
    float se = ex;
    #pragma unroll
    for (int s = 1; s < 64; s <<= 1) se += __shfl_xor(se, s);
    float lse = m + logf(se);
    float p = ex / se;
    float term = (lane < NCLS) ? p * logf(p + 1e-8f) : 0.0f;
    float ent = term;
    #pragma unroll
    for (int s = 1; s < 64; s <<= 1) ent += __shfl_xor(ent, s);
    ent = -ent;
    int lab = labels[row];
    float vl = __shfl(v, lab);           // logits[row][label]
    float cls = lse - vl;                // -log_softmax[label]

    // --- embeddings: L2-normalize -> bf16 ---
    const float4* src = reinterpret_cast<const float4*>(emb + (size_t)row * DIM);
    float4 x = src[lane];
    float ss = x.x*x.x + x.y*x.y + x.z*x.z + x.w*x.w;
    #pragma unroll
    for (int s = 1; s < 64; s <<= 1) ss += __shfl_xor(ss, s);
    float sc = 1.0f / fmaxf(sqrtf(ss), 1e-12f);
    ushort4 o;
    __hip_bfloat16 b0 = __float2bfloat16(x.x * sc);
    __hip_bfloat16 b1 = __float2bfloat16(x.y * sc);
    __hip_bfloat16 b2 = __float2bfloat16(x.z * sc);
    __hip_bfloat16 b3 = __float2bfloat16(x.w * sc);
    o.x = *reinterpret_cast<unsigned short*>(&b0);
    o.y = *reinterpret_cast<unsigned short*>(&b1);
    o.z = *reinterpret_cast<unsigned short*>(&b2);
    o.w = *reinterpret_cast<unsigned short*>(&b3);
    *reinterpret_cast<ushort4*>(e + (size_t)row * DIM + lane * 4) = o;

    if (lane == 0) {
        u[row] = ent / 4.04305127f;      // log(57)
        neg_sum[row] = 0.0f;             // zero before k_negsum (next grid)
        atomicAdd(&task_count[tasks[row]], 1);   // 57 addresses: fine
        scls[wave] = cls;
    }
    __syncthreads();
    if (threadIdx.x == 0) cls_part[blockIdx.x] = scls[0] + scls[1] + scls[2] + scls[3];
}

// ---- kernel 2: wave-parallel exclusive prefix scans --------------------------------
__global__ void k_prefix(const int* __restrict__ task_count, int* __restrict__ task_start,
                         int* __restrict__ task_cursor, int* __restrict__ pair_base) {
    int lane = threadIdx.x & 63;
    int c = (lane < NTASK) ? task_count[lane] : 0;
    int p = (lane < NTASK && c >= 2 && c < BSZ) ? c * (c - 1) : 0;
    int xc = c, xp = p;
    #pragma unroll
    for (int s = 1; s < 64; s <<= 1) {
        int yc = __shfl_up(xc, s), yp = __shfl_up(xp, s);
        if (lane >= s) { xc += yc; xp += yp; }
    }
    if (lane < NTASK) {
        task_start[lane]  = xc - c;
        task_cursor[lane] = xc - c;
        pair_base[lane]   = xp - p;
    }
}

// ---- kernel 3: counting-sort scatter (+rank) ---------------------------------------
__global__ void k_scatter(const int* __restrict__ tasks, int* __restrict__ task_cursor,
                          const int* __restrict__ task_start,
                          int* __restrict__ sorted, int* __restrict__ rank_) {
    int i = blockIdx.x * 256 + threadIdx.x;
    if (i < BSZ) {
        int t = tasks[i];
        int pos = atomicAdd(&task_cursor[t], 1);
        sorted[pos] = i;
        rank_[i] = pos - task_start[t];
    }
}

// ---- kernel 4: sim matrix, lower triangle, A-in-regs + double-buffered B in LDS ----
// A has zero block-level reuse -> full-K A fragments live in 64 VGPRs (no LDS, no
// ds_read). B (4-wave multicast) staged via global_load_lds into Bs[2][128][64],
// 2-phase schedule: issue stage(kk+1) BEFORE compute(kk); ONE barrier per K-step
// whose vmcnt(0) drain is covered by the compute phase. B keeps the verified
// source-preswizzle/read-XOR (bank conflicts = 0). Epilogue: exp both directions
// (row-reduce + col-reduce), posbuf stores both orientations (exactly-once).
__global__ __launch_bounds__(256, 2) void k_negsum_store(
        const unsigned short* __restrict__ E,
        const int* __restrict__ tasks, const int* __restrict__ rank_,
        const int* __restrict__ task_count, const int* __restrict__ pair_base,
        float* __restrict__ neg_sum, float* __restrict__ posbuf) {
    __shared__ unsigned short Bs[2][BN][BKE];   // 2 x 16 KB

    // XCD-aware swizzle (NTRI=2080 divisible by 8 -> bijective)
    int b = (blockIdx.x & 7) * (NTRI / 8) + (blockIdx.x >> 3);
    // decode lower triangle: b = bn*(bn+1)/2 + bm, bm <= bn
    int bn = (int)((sqrtf(8.0f * (float)b + 1.0f) - 1.0f) * 0.5f);
    while ((bn + 1) * (bn + 2) / 2 <= b) ++bn;
    while (bn * (bn + 1) / 2 > b) --bn;
    int bm = b - bn * (bn + 1) / 2;
    bool diag = (bm == bn);

    int wave = threadIdx.x >> 6;
    int lane = threadIdx.x & 63;
    int tid  = threadIdx.x;
    int g  = lane >> 4;                      // 0..3
    int lr = lane & 15;
    int m0 = bm * BM;                        // rows (A)
    int n0 = bn * BN;                        // cols (B)
    int sw = lr & 7;                         // read-side XOR (row&7 == lr&7)

    // ---- A: full K=256 into registers (16 x dwordx4) ----
    bf16x8 a0r[8], a1r[8];
    {
        const unsigned short* ar0 = E + (size_t)(m0 + wave * 32 + lr) * DIM + g * 8;
        #pragma unroll
        for (int ks = 0; ks < 8; ++ks) {
            a0r[ks] = *reinterpret_cast<const bf16x8*>(ar0 + ks * 32);
            a1r[ks] = *reinterpret_cast<const bf16x8*>(ar0 + 16 * DIM + ks * 32);
        }
    }

    f32x4 acc[2][8] = {};

    #define STAGE_B(KK, BUF)                                                          \
        {                                                                             \
            _Pragma("unroll")                                                         \
            for (int l = 0; l < 4; ++l) {                                             \
                int flat = l * 256 + tid;            /* 16B chunk index */            \
                int row = flat >> 3, kb = flat & 7;                                   \
                int kbs = kb ^ (row & 7);            /* pre-swizzled source chunk */  \
                const unsigned short* gb =                                            \
                    E + (size_t)(n0 + row) * DIM + (KK) * BKE + kbs * 8;              \
                unsigned short* lb =                                                  \
                    &Bs[BUF][0][0] + (size_t)(l * 256 + wave * 64) * 8;               \
                gload_lds16(gb, lb);                                                  \
            }                                                                         \
        }

    STAGE_B(0, 0);
    __syncthreads();                          // drains stage(0) (+A loads)

    #pragma unroll
    for (int kk = 0; kk < 4; ++kk) {
        if (kk < 3) STAGE_B(kk + 1, (kk + 1) & 1);   // prefetch next under compute
        const int cur = kk & 1;
        #pragma unroll
        for (int ks2 = 0; ks2 < 2; ++ks2) {
            int cs = ((ks2 * 4 + g) ^ sw) * 8;       // swizzled LDS offset (elems)
            int ks = kk * 2 + ks2;
            #pragma unroll
            for (int f = 0; f < 8; ++f) {
                bf16x8 bfr = *reinterpret_cast<const bf16x8*>(&Bs[cur][f * 16 + lr][cs]);
                acc[0][f] = __builtin_amdgcn_mfma_f32_16x16x32_bf16(a0r[ks], bfr, acc[0][f], 0, 0, 0);
                acc[1][f] = __builtin_amdgcn_mfma_f32_16x16x32_bf16(a1r[ks], bfr, acc[1][f], 0, 0, 0);
            }
        }
        if (kk < 3) __syncthreads();          // vmcnt drain covered by compute above
    }
    #undef STAGE_B

    // ---- epilogue ----
    int colt[8], colrk[8];
    #pragma unroll
    for (int f = 0; f < 8; ++f) {
        int col = n0 + f * 16 + lr;
        colt[f]  = tasks[col];
        colrk[f] = rank_[col];
    }
    float csum[8] = {};                      // col-direction exp partials (off-diag)

    #pragma unroll
    for (int mi = 0; mi < 2; ++mi) {
        #pragma unroll
        for (int r = 0; r < 4; ++r) {
            int row = m0 + wave * 32 + mi * 16 + g * 4 + r;
            int rt  = tasks[row];
            int rrk = rank_[row];
            int ct  = task_count[rt];
            int pb  = pair_base[rt];
            bool vt = (ct >= 2 && ct < BSZ);
            float s = 0.0f;
            #pragma unroll
            for (int f = 0; f < 8; ++f) {
                float sv = acc[mi][f][r] * INV_T;
                int col = n0 + f * 16 + lr;
                if (colt[f] != rt) {
                    float ev = __expf(sv);
                    s += ev;                               // -> neg_sum[row]
                    csum[f] += ev;                         // -> neg_sum[col] (off-diag)
                } else if (col != row && vt) {
                    int cr = colrk[f];
                    int idx = pb + rrk * (ct - 1) + cr - (cr > rrk ? 1 : 0);
                    if (idx < PAIR_CAP) posbuf[idx] = sv;  // (i,j)
                    if (!diag) {
                        int jdx = pb + cr * (ct - 1) + rrk - (rrk > cr ? 1 : 0);
                        if (jdx < PAIR_CAP) posbuf[jdx] = sv;  // (j,i) via symmetry
                    }
                }
            }
            s += __shfl_xor(s, 1); s += __shfl_xor(s, 2);
            s += __shfl_xor(s, 4); s += __shfl_xor(s, 8);
            if (lr == 0) atomicAdd(&neg_sum[row], s);
        }
    }
    if (!diag) {
        #pragma unroll
        for (int f = 0; f < 8; ++f) {
            float cs = csum[f];
            cs += __shfl_xor(cs, 16); cs += __shfl_xor(cs, 32);
            if (g == 0) atomicAdd(&neg_sum[n0 + f * 16 + lr], cs);
        }
    }
}

// ---- kernel 5: per-anchor positive-pair loss from stored sims ----------------------
__global__ __launch_bounds__(256) void k_pair(
        const int* __restrict__ sorted, const int* __restrict__ tasks,
        const int* __restrict__ rank_, const int* __restrict__ task_count,
        const int* __restrict__ pair_base, const float* __restrict__ neg_sum,
        const float* __restrict__ u, const float* __restrict__ posbuf,
        float* __restrict__ contr_part) {
    __shared__ float sp[4];
    int wave = threadIdx.x >> 6;
    int lane = threadIdx.x & 63;
    int a = blockIdx.x * 4 + wave;           // position in sorted order
    float wsum = 0.0f;
    int i = sorted[a];
    int t = tasks[i];
    int c = task_count[t];
    if (c >= 2 && c < BSZ) {
        int base = pair_base[t] + rank_[i] * (c - 1);
        float Ci = neg_sum[i] + 1e-8f;
        float local = 0.0f;
        for (int q = lane; q < c - 1; q += 64) {
            float sv = posbuf[base + q];
            local += logf(__expf(sv) + Ci) - sv;   // -log(exp(s)/(exp(s)+C))
        }
        #pragma unroll
        for (int s = 1; s < 64; s <<= 1) local += __shfl_xor(local, s);
        wsum = u[i] * local;
    }
    if (lane == 0) sp[wave] = wsum;
    __syncthreads();
    if (threadIdx.x == 0) contr_part[blockIdx.x] = sp[0] + sp[1] + sp[2] + sp[3];
}

// ---- kernel 6: final reduce + combine ----------------------------------------------
__global__ __launch_bounds__(256) void k_final(
        const int* __restrict__ task_count, const float* __restrict__ cls_part,
        const float* __restrict__ contr_part, float* __restrict__ out) {
    __shared__ float sc[4], sp[4];
    int tid = threadIdx.x, wave = tid >> 6, lane = tid & 63;
    float c1 = 0.0f, c2 = 0.0f;
    for (int i = tid; i < BSZ / 4; i += 256) { c1 += cls_part[i]; c2 += contr_part[i]; }
    #pragma unroll
    for (int s = 1; s < 64; s <<= 1) { c1 += __shfl_xor(c1, s); c2 += __shfl_xor(c2, s); }
    if (lane == 0) { sc[wave] = c1; sp[wave] = c2; }
    long long cnt = 0;
    if (tid < 64) {
        int c = (lane < NTASK) ? task_count[lane] : 0;
        cnt = (c >= 2 && c < BSZ) ? (long long)c * (c - 1) : 0;
        #pragma unroll
        for (int s = 1; s < 64; s <<= 1) cnt += __shfl_xor(cnt, s);
    }
    __syncthreads();
    if (tid == 0) {
        float cls = (sc[0] + sc[1] + sc[2] + sc[3]) / (float)BSZ;
        float con = sp[0] + sp[1] + sp[2] + sp[3];
        out[0] = 0.7f * cls + 0.3f * (cnt > 0 ? con / (float)cnt : 0.0f);
    }
}

extern "C" void kernel_launch(void* const* d_in, const int* in_sizes, int n_in,
                              void* d_out, int out_size, void* d_ws, size_t ws_size,
                              hipStream_t stream) {
    const float* logits = (const float*)d_in[0];
    const float* emb    = (const float*)d_in[1];
    const int*   labels = (const int*)d_in[2];
    const int*   tasks  = (const int*)d_in[3];
    float* out = (float*)d_out;

    char* ws = (char*)d_ws;
    // layout (4B units):
    // header[512]: [64..]=task_count [128..]=task_start [192..]=task_cursor [256..]=pair_base
    // neg_sum[BSZ], u[BSZ], sorted[BSZ], rank[BSZ], cls_part[2048], contr_part[2048],
    // E bf16[BSZ*DIM], posbuf[PAIR_CAP]
    int*   task_count  = (int*)ws + 64;
    int*   task_start  = (int*)ws + 128;
    int*   task_cursor = (int*)ws + 192;
    int*   pair_base   = (int*)ws + 256;
    float* neg_sum     = (float*)ws + 512;
    float* u           = neg_sum + BSZ;
    int*   sorted      = (int*)ws + 512 + 2 * BSZ;
    int*   rank_       = (int*)ws + 512 + 3 * BSZ;
    float* cls_part    = (float*)ws + 512 + 4 * BSZ;
    float* contr_part  = cls_part + 2048;
    unsigned short* e  = (unsigned short*)(ws + (size_t)(512 + 4 * BSZ + 4096) * 4);
    float* posbuf      = (float*)((char*)e + (size_t)BSZ * DIM * 2);

    // zero header only (task_count); neg_sum zeroed inside k_prep
    hipMemsetAsync(ws, 0, 512 * 4, stream);

    k_prep   <<<BSZ / 4,   256, 0, stream>>>(logits, emb, labels, tasks, u, cls_part,
                                             task_count, e, neg_sum);
    k_prefix <<<1,         64,  0, stream>>>(task_count, task_start, task_cursor, pair_base);
    k_scatter<<<BSZ / 256, 256, 0, stream>>>(tasks, task_cursor, task_start, sorted, rank_);
    k_negsum_store<<<NTRI, 256, 0, stream>>>(e, tasks, rank_, task_count, pair_base,
                                             neg_sum, posbuf);
    k_pair   <<<BSZ / 4,   256, 0, stream>>>(sorted, tasks, rank_, task_count, pair_base,
                                             neg_sum, u, posbuf, contr_part);
    k_final  <<<1,         256, 0, stream>>>(task_count, cls_part, contr_part, out);
}